// Round 1
// baseline (392.999 us; speedup 1.0000x reference)
//
#include <hip/hip_runtime.h>
#include <hip/hip_bf16.h>

typedef __bf16 bf16x8 __attribute__((ext_vector_type(8)));
typedef float  f32x4  __attribute__((ext_vector_type(4)));

typedef __attribute__((address_space(3))) unsigned int as3_u32;
typedef __attribute__((address_space(1))) unsigned int as1_u32;

__device__ __forceinline__ void gld_lds16(const void* gptr, void* lptr){
  __builtin_amdgcn_global_load_lds((const as1_u32*)gptr, (as3_u32*)lptr, 16, 0, 0);
}

// ---------------- weight convert + transpose: in[R][C] f32 -> out[C][R] bf16
__global__ __launch_bounds__(256) void transpose_cvt(const float* __restrict__ in,
                                                     __bf16* __restrict__ out, int R, int C){
  __shared__ float tile[32][33];
  const int c0 = blockIdx.x*32, r0 = blockIdx.y*32;
  const int tx = threadIdx.x, ty = threadIdx.y;
  #pragma unroll
  for (int i=0;i<32;i+=8)
    tile[ty+i][tx] = in[(size_t)(r0+ty+i)*C + c0+tx];
  __syncthreads();
  #pragma unroll
  for (int i=0;i<32;i+=8)
    out[(size_t)(c0+ty+i)*R + r0+tx] = (__bf16)tile[tx][ty+i];
}

// ---------------- layernorm: rows of 1024 f32 -> bf16 (computes (x-mu)/sqrt(var+eps)*g+b)
__global__ __launch_bounds__(256) void ln_kernel(const float* __restrict__ x, const float* __restrict__ g,
                                                 const float* __restrict__ b, __bf16* __restrict__ out){
  const int row = blockIdx.x, t = threadIdx.x;
  const float4 v = ((const float4*)(x + (size_t)row*1024))[t];
  float s = v.x+v.y+v.z+v.w;
  #pragma unroll
  for (int m=1;m<64;m<<=1) s += __shfl_xor(s, m);
  __shared__ float red[8];
  if ((t&63)==0) red[t>>6] = s;
  __syncthreads();
  const float mu = (red[0]+red[1]+red[2]+red[3]) * (1.f/1024.f);
  const float d0=v.x-mu, d1=v.y-mu, d2=v.z-mu, d3=v.w-mu;
  float sq = d0*d0+d1*d1+d2*d2+d3*d3;
  #pragma unroll
  for (int m=1;m<64;m<<=1) sq += __shfl_xor(sq, m);
  if ((t&63)==0) red[4+(t>>6)] = sq;
  __syncthreads();
  const float var = (red[4]+red[5]+red[6]+red[7]) * (1.f/1024.f);
  const float inv = rsqrtf(var + 1e-12f);
  const float4 gv = ((const float4*)g)[t];
  const float4 bv = ((const float4*)b)[t];
  union { __bf16 h[4]; uint2 u; } pk;
  pk.h[0]=(__bf16)(d0*inv*gv.x+bv.x); pk.h[1]=(__bf16)(d1*inv*gv.y+bv.y);
  pk.h[2]=(__bf16)(d2*inv*gv.z+bv.z); pk.h[3]=(__bf16)(d3*inv*gv.w+bv.w);
  *(uint2*)(out + (size_t)row*1024 + t*4) = pk.u;
}

// ---------------- GEMM: C[M,N] = A[M,K](bf16,row) @ Bt[N,K](bf16,row)^T + bias, fused epilogues
// MODE 0: QKV scatter -> Q[bh][s][d], K[bh][s][d], Vt[bh][d][s]  (bf16)
// MODE 1: outF = C + bias + resid (fp32)
// MODE 2: outB = gelu_exact(C) (bf16), no bias
template<int MODE>
__global__ __launch_bounds__(256) void gemm_bt(
    const __bf16* __restrict__ A, const __bf16* __restrict__ Bt,
    const float* __restrict__ bias, const float* __restrict__ resid,
    float* __restrict__ outF, __bf16* __restrict__ outB,
    __bf16* __restrict__ qO, __bf16* __restrict__ kO, __bf16* __restrict__ vtO,
    int M, int N, int K)
{
  __shared__ __align__(16) __bf16 As[128*32];
  __shared__ __align__(16) __bf16 Bs[128*32];
  const int tid = threadIdx.x;
  const int lane = tid & 63, wave = tid >> 6;
  const int wr = wave >> 1, wc = wave & 1;
  const int l15 = lane & 15, lg = lane >> 4;
  const int bm = blockIdx.x, bn = blockIdx.y;
  const __bf16* Ab = A  + (size_t)bm*128*K;
  const __bf16* Bb = Bt + (size_t)bn*128*K;
  f32x4 acc[4][4] = {};
  const int r0 = tid >> 2;        // 0..63  (row within half-tile)
  const int c0 = (tid & 3) * 8;   // 0..24  (k-offset, 8 bf16 = 16B)
  char* lA0 = (char*)As + wave*1024;
  char* lA1 = (char*)As + 4096 + wave*1024;
  char* lB0 = (char*)Bs + wave*1024;
  char* lB1 = (char*)Bs + 4096 + wave*1024;
  const int nk = K >> 5;
  for (int kt = 0; kt < nk; ++kt){
    __syncthreads();                       // protect LDS from prior iter readers
    const int k0 = kt*32;
    gld_lds16(Ab + (size_t)r0*K      + k0 + c0, lA0);
    gld_lds16(Ab + (size_t)(r0+64)*K + k0 + c0, lA1);
    gld_lds16(Bb + (size_t)r0*K      + k0 + c0, lB0);
    gld_lds16(Bb + (size_t)(r0+64)*K + k0 + c0, lB1);
    __syncthreads();                       // drains vmcnt (guide: full drain at barrier)
    bf16x8 af[4], bfv[4];
    #pragma unroll
    for (int i=0;i<4;++i){
      af[i]  = *(const bf16x8*)&As[(wr*64 + i*16 + l15)*32 + lg*8];
      bfv[i] = *(const bf16x8*)&Bs[(wc*64 + i*16 + l15)*32 + lg*8];
    }
    #pragma unroll
    for (int i=0;i<4;++i)
      #pragma unroll
      for (int j=0;j<4;++j)
        acc[i][j] = __builtin_amdgcn_mfma_f32_16x16x32_bf16(af[i], bfv[j], acc[i][j], 0,0,0);
  }
  // epilogue: C row = bm*128 + wr*64 + i*16 + lg*4 + r ; col = bn*128 + wc*64 + j*16 + l15
  #pragma unroll
  for (int i=0;i<4;++i){
    #pragma unroll
    for (int j=0;j<4;++j){
      const int col = bn*128 + wc*64 + j*16 + l15;
      float bv;
      if constexpr (MODE==2) bv = 0.f; else bv = bias[col];
      #pragma unroll
      for (int r=0;r<4;++r){
        const int row = bm*128 + wr*64 + i*16 + lg*4 + r;
        float v = acc[i][j][r] + bv;
        if constexpr (MODE==0){
          const int b_ = row >> 11, s_ = row & 2047;
          if (col < 1024){
            const int h = col>>6, d = col&63;
            qO[((size_t)(b_*16+h)*2048 + s_)*64 + d] = (__bf16)v;
          } else if (col < 2048){
            const int h = (col-1024)>>6, d = (col-1024)&63;
            kO[((size_t)(b_*16+h)*2048 + s_)*64 + d] = (__bf16)v;
          } else {
            const int h = (col-2048)>>6, d = (col-2048)&63;
            vtO[((size_t)(b_*16+h)*64 + d)*2048 + s_] = (__bf16)v;
          }
        } else if constexpr (MODE==1){
          outF[(size_t)row*N + col] = v + resid[(size_t)row*N + col];
        } else {
          const float gl = 0.5f*v*(1.f + erff(v*0.70710678118f));
          outB[(size_t)row*N + col] = (__bf16)gl;
        }
      }
    }
  }
}

// ---------------- flash attention, causal. 1 wave/block, 32 q-rows, KVBLK=32, HD=64.
// Q,K: [bh][s][64] bf16 ; Vt: [bh][64][s] bf16 ; out: [b*2048+s][h*64+d] bf16
__global__ __launch_bounds__(64) void attn_kernel(
    const __bf16* __restrict__ Q, const __bf16* __restrict__ K,
    const __bf16* __restrict__ Vt, __bf16* __restrict__ out)
{
  const int lane = threadIdx.x;
  const int l15 = lane & 15, lg = lane >> 4;
  const int bh = blockIdx.y;
  const int qt = blockIdx.x;
  const int qbase = qt*32;
  const __bf16* Qh = Q  + (size_t)bh*2048*64;
  const __bf16* Kh = K  + (size_t)bh*2048*64;
  const __bf16* Vh = Vt + (size_t)bh*64*2048;
  bf16x8 qf[2][2];
  #pragma unroll
  for (int q=0;q<2;++q)
    #pragma unroll
    for (int f=0;f<2;++f)
      qf[q][f] = *(const bf16x8*)&Qh[(size_t)(qbase + q*16 + l15)*64 + f*32 + lg*8];
  f32x4 oacc[2][4] = {};
  float mrun[2][4], lrun[2][4];
  #pragma unroll
  for (int q=0;q<2;++q)
    #pragma unroll
    for (int r=0;r<4;++r){ mrun[q][r] = -1e30f; lrun[q][r] = 0.f; }
  __shared__ __align__(16) __bf16 Pl[2][16*32];
  const int nst = qt + 1;
  for (int st=0; st<nst; ++st){
    const int kv0 = st*32;
    bf16x8 kf[2][2];
    #pragma unroll
    for (int t=0;t<2;++t)
      #pragma unroll
      for (int f=0;f<2;++f)
        kf[t][f] = *(const bf16x8*)&Kh[(size_t)(kv0 + t*16 + l15)*64 + f*32 + lg*8];
    f32x4 sc[2][2] = {};
    #pragma unroll
    for (int q=0;q<2;++q)
      #pragma unroll
      for (int t=0;t<2;++t){
        sc[q][t] = __builtin_amdgcn_mfma_f32_16x16x32_bf16(qf[q][0], kf[t][0], sc[q][t], 0,0,0);
        sc[q][t] = __builtin_amdgcn_mfma_f32_16x16x32_bf16(qf[q][1], kf[t][1], sc[q][t], 0,0,0);
      }
    float corr[2][4];
    #pragma unroll
    for (int q=0;q<2;++q){
      #pragma unroll
      for (int r=0;r<4;++r){
        const int grow = qbase + q*16 + lg*4 + r;
        float s0 = sc[q][0][r]*0.125f;
        float s1 = sc[q][1][r]*0.125f;
        if (kv0 + l15      > grow) s0 = -1e30f;
        if (kv0 + 16 + l15 > grow) s1 = -1e30f;
        float mx = fmaxf(s0, s1);
        #pragma unroll
        for (int m=1;m<16;m<<=1) mx = fmaxf(mx, __shfl_xor(mx, m));
        const float nm = fmaxf(mrun[q][r], mx);
        const float co = __expf(mrun[q][r] - nm);
        mrun[q][r] = nm;
        corr[q][r] = co;
        const float p0 = __expf(s0 - nm);
        const float p1 = __expf(s1 - nm);
        sc[q][0][r] = p0; sc[q][1][r] = p1;
        float rs = p0 + p1;
        #pragma unroll
        for (int m=1;m<16;m<<=1) rs += __shfl_xor(rs, m);
        lrun[q][r] = lrun[q][r]*co + rs;
      }
    }
    #pragma unroll
    for (int q=0;q<2;++q)
      #pragma unroll
      for (int c=0;c<4;++c)
        #pragma unroll
        for (int r=0;r<4;++r)
          oacc[q][c][r] *= corr[q][r];
    bf16x8 vf[4];
    #pragma unroll
    for (int c=0;c<4;++c)
      vf[c] = *(const bf16x8*)&Vh[(size_t)(c*16 + l15)*2048 + kv0 + lg*8];
    __syncthreads();
    #pragma unroll
    for (int q=0;q<2;++q)
      #pragma unroll
      for (int t=0;t<2;++t)
        #pragma unroll
        for (int r=0;r<4;++r)
          Pl[q][(lg*4+r)*32 + t*16 + l15] = (__bf16)sc[q][t][r];
    __syncthreads();
    #pragma unroll
    for (int q=0;q<2;++q){
      bf16x8 pa = *(const bf16x8*)&Pl[q][l15*32 + lg*8];
      #pragma unroll
      for (int c=0;c<4;++c)
        oacc[q][c] = __builtin_amdgcn_mfma_f32_16x16x32_bf16(pa, vf[c], oacc[q][c], 0,0,0);
    }
  }
  const int b_ = bh >> 4, h_ = bh & 15;
  #pragma unroll
  for (int q=0;q<2;++q)
    #pragma unroll
    for (int c=0;c<4;++c)
      #pragma unroll
      for (int r=0;r<4;++r){
        const int row = qbase + q*16 + lg*4 + r;
        const float v = oacc[q][c][r] / lrun[q][r];
        out[((size_t)(b_*2048 + row))*1024 + h_*64 + c*16 + l15] = (__bf16)v;
      }
}

extern "C" void kernel_launch(void* const* d_in, const int* in_sizes, int n_in,
                              void* d_out, int out_size, void* d_ws, size_t ws_size,
                              hipStream_t stream) {
  const float* x      = (const float*)d_in[0];
  const float* ln1_g  = (const float*)d_in[1];
  const float* ln1_b  = (const float*)d_in[2];
  const float* w_qkv  = (const float*)d_in[3];
  const float* b_qkv  = (const float*)d_in[4];
  const float* w_dense= (const float*)d_in[5];
  const float* b_dense= (const float*)d_in[6];
  const float* ln2_g  = (const float*)d_in[7];
  const float* ln2_b  = (const float*)d_in[8];
  const float* w_fc1  = (const float*)d_in[9];
  const float* w_fc2  = (const float*)d_in[10];
  const float* b_fc2  = (const float*)d_in[11];

  char* ws = (char*)d_ws;
  __bf16* wqkvT  = (__bf16*)(ws + 0);          // [3072][1024]  6 MB
  __bf16* wdenT  = (__bf16*)(ws + 6291456);    // [1024][1024]  2 MB
  __bf16* wfc1T  = (__bf16*)(ws + 8388608);    // [2048][1024]  4 MB
  __bf16* wfc2T  = (__bf16*)(ws + 12582912);   // [1024][2048]  4 MB
  __bf16* xn     = (__bf16*)(ws + 16777216);   // [4096][1024]  8 MB
  __bf16* Qb     = (__bf16*)(ws + 25165824);   // [32][2048][64] 8 MB
  __bf16* Kb     = (__bf16*)(ws + 33554432);   // [32][2048][64] 8 MB
  __bf16* Vtb    = (__bf16*)(ws + 41943040);   // [32][64][2048] 8 MB
  __bf16* attnb  = (__bf16*)(ws + 50331648);   // [4096][1024]  8 MB
  float*  outf   = (float*) (ws + 58720256);   // [4096][1024] 16 MB
  __bf16* mb     = (__bf16*)(ws + 75497472);   // [4096][1024]  8 MB
  __bf16* h1b    = (__bf16*)(ws + 83886080);   // [4096][2048] 16 MB

  dim3 blkT(32,8);
  // weight convert + transpose (bf16, B^T layout)
  transpose_cvt<<<dim3(3072/32, 1024/32), blkT, 0, stream>>>(w_qkv,   wqkvT, 1024, 3072);
  transpose_cvt<<<dim3(1024/32, 1024/32), blkT, 0, stream>>>(w_dense, wdenT, 1024, 1024);
  transpose_cvt<<<dim3(2048/32, 1024/32), blkT, 0, stream>>>(w_fc1,   wfc1T, 1024, 2048);
  transpose_cvt<<<dim3(1024/32, 2048/32), blkT, 0, stream>>>(w_fc2,   wfc2T, 2048, 1024);
  // LN1
  ln_kernel<<<4096, 256, 0, stream>>>(x, ln1_g, ln1_b, xn);
  // QKV GEMM + scatter
  gemm_bt<0><<<dim3(32,24), 256, 0, stream>>>(xn, wqkvT, b_qkv, nullptr,
                                              nullptr, nullptr, Qb, Kb, Vtb, 4096, 3072, 1024);
  // attention
  attn_kernel<<<dim3(64,32), 64, 0, stream>>>(Qb, Kb, Vtb, attnb);
  // dense + residual -> outf (fp32)
  gemm_bt<1><<<dim3(32,8), 256, 0, stream>>>(attnb, wdenT, b_dense, x,
                                             outf, nullptr, nullptr, nullptr, nullptr, 4096, 1024, 1024);
  // LN2
  ln_kernel<<<4096, 256, 0, stream>>>(outf, ln2_g, ln2_b, mb);
  // FC1 + GELU
  gemm_bt<2><<<dim3(32,16), 256, 0, stream>>>(mb, wfc1T, nullptr, nullptr,
                                              nullptr, h1b, nullptr, nullptr, nullptr, 4096, 2048, 1024);
  // FC2 + bias + residual -> d_out (fp32)
  gemm_bt<1><<<dim3(32,8), 256, 0, stream>>>(h1b, wfc2T, b_fc2, outf,
                                             (float*)d_out, nullptr, nullptr, nullptr, nullptr, 4096, 1024, 2048);
}

// Round 2
// 322.104 us; speedup vs baseline: 1.2201x; 1.2201x over previous
//
#include <hip/hip_runtime.h>
#include <hip/hip_bf16.h>

typedef __bf16 bf16x8 __attribute__((ext_vector_type(8)));
typedef float  f32x4  __attribute__((ext_vector_type(4)));

typedef __attribute__((address_space(3))) unsigned int as3_u32;
typedef __attribute__((address_space(1))) unsigned int as1_u32;

__device__ __forceinline__ void gld_lds16(const void* gptr, void* lptr){
  __builtin_amdgcn_global_load_lds((const as1_u32*)gptr, (as3_u32*)lptr, 16, 0, 0);
}

// ---------------- weight convert + transpose: in[R][C] f32 -> out[C][R] bf16
__global__ __launch_bounds__(256) void transpose_cvt(const float* __restrict__ in,
                                                     __bf16* __restrict__ out, int R, int C){
  __shared__ float tile[32][33];
  const int c0 = blockIdx.x*32, r0 = blockIdx.y*32;
  const int tx = threadIdx.x, ty = threadIdx.y;
  #pragma unroll
  for (int i=0;i<32;i+=8)
    tile[ty+i][tx] = in[(size_t)(r0+ty+i)*C + c0+tx];
  __syncthreads();
  #pragma unroll
  for (int i=0;i<32;i+=8)
    out[(size_t)(c0+ty+i)*R + r0+tx] = (__bf16)tile[tx][ty+i];
}

// ---------------- layernorm: rows of 1024 f32 -> bf16
__global__ __launch_bounds__(256) void ln_kernel(const float* __restrict__ x, const float* __restrict__ g,
                                                 const float* __restrict__ b, __bf16* __restrict__ out){
  const int row = blockIdx.x, t = threadIdx.x;
  const float4 v = ((const float4*)(x + (size_t)row*1024))[t];
  float s = v.x+v.y+v.z+v.w;
  #pragma unroll
  for (int m=1;m<64;m<<=1) s += __shfl_xor(s, m);
  __shared__ float red[8];
  if ((t&63)==0) red[t>>6] = s;
  __syncthreads();
  const float mu = (red[0]+red[1]+red[2]+red[3]) * (1.f/1024.f);
  const float d0=v.x-mu, d1=v.y-mu, d2=v.z-mu, d3=v.w-mu;
  float sq = d0*d0+d1*d1+d2*d2+d3*d3;
  #pragma unroll
  for (int m=1;m<64;m<<=1) sq += __shfl_xor(sq, m);
  if ((t&63)==0) red[4+(t>>6)] = sq;
  __syncthreads();
  const float var = (red[4]+red[5]+red[6]+red[7]) * (1.f/1024.f);
  const float inv = rsqrtf(var + 1e-12f);
  const float4 gv = ((const float4*)g)[t];
  const float4 bv = ((const float4*)b)[t];
  union { __bf16 h[4]; uint2 u; } pk;
  pk.h[0]=(__bf16)(d0*inv*gv.x+bv.x); pk.h[1]=(__bf16)(d1*inv*gv.y+bv.y);
  pk.h[2]=(__bf16)(d2*inv*gv.z+bv.z); pk.h[3]=(__bf16)(d3*inv*gv.w+bv.w);
  *(uint2*)(out + (size_t)row*1024 + t*4) = pk.u;
}

// ---------------- GEMM: C[M,N] = A[M,K](bf16,row) @ Bt[N,K](bf16,row)^T + bias, fused epilogues
template<int MODE>
__global__ __launch_bounds__(256) void gemm_bt(
    const __bf16* __restrict__ A, const __bf16* __restrict__ Bt,
    const float* __restrict__ bias, const float* __restrict__ resid,
    float* __restrict__ outF, __bf16* __restrict__ outB,
    __bf16* __restrict__ qO, __bf16* __restrict__ kO, __bf16* __restrict__ vtO,
    int M, int N, int K)
{
  __shared__ __align__(16) __bf16 As[128*32];
  __shared__ __align__(16) __bf16 Bs[128*32];
  const int tid = threadIdx.x;
  const int lane = tid & 63, wave = tid >> 6;
  const int wr = wave >> 1, wc = wave & 1;
  const int l15 = lane & 15, lg = lane >> 4;
  const int bm = blockIdx.x, bn = blockIdx.y;
  const __bf16* Ab = A  + (size_t)bm*128*K;
  const __bf16* Bb = Bt + (size_t)bn*128*K;
  f32x4 acc[4][4] = {};
  const int r0 = tid >> 2;
  const int c0 = (tid & 3) * 8;
  char* lA0 = (char*)As + wave*1024;
  char* lA1 = (char*)As + 4096 + wave*1024;
  char* lB0 = (char*)Bs + wave*1024;
  char* lB1 = (char*)Bs + 4096 + wave*1024;
  const int nk = K >> 5;
  for (int kt = 0; kt < nk; ++kt){
    __syncthreads();
    const int k0 = kt*32;
    gld_lds16(Ab + (size_t)r0*K      + k0 + c0, lA0);
    gld_lds16(Ab + (size_t)(r0+64)*K + k0 + c0, lA1);
    gld_lds16(Bb + (size_t)r0*K      + k0 + c0, lB0);
    gld_lds16(Bb + (size_t)(r0+64)*K + k0 + c0, lB1);
    __syncthreads();
    bf16x8 af[4], bfv[4];
    #pragma unroll
    for (int i=0;i<4;++i){
      af[i]  = *(const bf16x8*)&As[(wr*64 + i*16 + l15)*32 + lg*8];
      bfv[i] = *(const bf16x8*)&Bs[(wc*64 + i*16 + l15)*32 + lg*8];
    }
    #pragma unroll
    for (int i=0;i<4;++i)
      #pragma unroll
      for (int j=0;j<4;++j)
        acc[i][j] = __builtin_amdgcn_mfma_f32_16x16x32_bf16(af[i], bfv[j], acc[i][j], 0,0,0);
  }
  #pragma unroll
  for (int i=0;i<4;++i){
    #pragma unroll
    for (int j=0;j<4;++j){
      const int col = bn*128 + wc*64 + j*16 + l15;
      float bv;
      if constexpr (MODE==2) bv = 0.f; else bv = bias[col];
      #pragma unroll
      for (int r=0;r<4;++r){
        const int row = bm*128 + wr*64 + i*16 + lg*4 + r;
        float v = acc[i][j][r] + bv;
        if constexpr (MODE==0){
          const int b_ = row >> 11, s_ = row & 2047;
          if (col < 1024){
            const int h = col>>6, d = col&63;
            qO[((size_t)(b_*16+h)*2048 + s_)*64 + d] = (__bf16)v;
          } else if (col < 2048){
            const int h = (col-1024)>>6, d = (col-1024)&63;
            kO[((size_t)(b_*16+h)*2048 + s_)*64 + d] = (__bf16)v;
          } else {
            const int h = (col-2048)>>6, d = (col-2048)&63;
            vtO[((size_t)(b_*16+h)*64 + d)*2048 + s_] = (__bf16)v;
          }
        } else if constexpr (MODE==1){
          outF[(size_t)row*N + col] = v + resid[(size_t)row*N + col];
        } else {
          const float gl = 0.5f*v*(1.f + erff(v*0.70710678118f));
          outB[(size_t)row*N + col] = (__bf16)gl;
        }
      }
    }
  }
}

// ---------------- flash attention v2, causal.
// Block: 256 threads / 4 waves, 64 q-rows (16/wave). KVBLK=64 staged in LDS (XOR-swizzled).
// Q,K: [bh][s][64] bf16 ; Vt: [bh][64][s] bf16 ; out: [b*2048+s][h*64+d] bf16
__global__ __launch_bounds__(256) void attn_kernel(
    const __bf16* __restrict__ Q, const __bf16* __restrict__ K,
    const __bf16* __restrict__ Vt, __bf16* __restrict__ out)
{
  __shared__ __align__(16) __bf16 Ks[64*64];
  __shared__ __align__(16) __bf16 Vs[64*64];
  __shared__ __align__(16) __bf16 Pl[4][16*64];
  const int tid = threadIdx.x;
  const int lane = tid & 63, wave = tid >> 6;
  const int l15 = lane & 15, lg = lane >> 4;
  const int bh = blockIdx.y;
  const int qblk = (int)(gridDim.x - 1) - blockIdx.x;   // longest blocks first
  const int qb = qblk * 64;
  const int qw = qb + wave*16;                          // wave's first q-row
  const __bf16* Qh = Q + (size_t)bh*2048*64;
  const char*  Khc = (const char*)(K  + (size_t)bh*2048*64);
  const char*  Vhc = (const char*)(Vt + (size_t)bh*64*2048);

  // Q fragments, pre-scaled by 1/sqrt(64)=0.125 (exact in bf16)
  bf16x8 qf[2];
  #pragma unroll
  for (int f=0;f<2;++f){
    bf16x8 t8 = *(const bf16x8*)&Qh[(size_t)(qw + l15)*64 + f*32 + lg*8];
    #pragma unroll
    for (int j=0;j<8;++j) t8[j] = (__bf16)((float)t8[j] * 0.125f);
    qf[f] = t8;
  }

  f32x4 oacc[4] = {};
  float mrun[4], lrun[4];
  #pragma unroll
  for (int r=0;r<4;++r){ mrun[r] = -1e30f; lrun[r] = 0.f; }

  // staging source swizzle: LDS[row][b16] = G[row][b16 ^ ((row&7)<<4)], row&7 == lane>>3
  const int swz_st = (((lane&7) ^ (lane>>3)) << 4);
  const int rswz_r = ((l15 & 7) << 4);                  // read-side row swizzle (row%8 == l15%8)
  char* Pw = (char*)&Pl[wave][0];

  const int nst = qblk + 1;
  for (int st = 0; st < nst; ++st){
    const int kv0 = st*64;
    __syncthreads();                                    // prev compute done before overwrite
    #pragma unroll
    for (int rr=0; rr<2; ++rr){
      const int row = rr*32 + wave*8 + (lane>>3);
      gld_lds16(Khc + (size_t)(kv0+row)*128 + swz_st, (char*)Ks + rr*4096 + wave*1024);
      gld_lds16(Vhc + (size_t)row*4096 + (size_t)kv0*2 + swz_st, (char*)Vs + rr*4096 + wave*1024);
    }
    __syncthreads();                                    // drains vmcnt: tiles ready

    // QK^T : sc[t][r] = score(q = qw+lg*4+r, k = kv0 + t*16 + l15), pre-scaled
    f32x4 sc[4] = {};
    #pragma unroll
    for (int t=0;t<4;++t){
      const int row = t*16 + l15;
      bf16x8 k0 = *(const bf16x8*)((const char*)Ks + row*128 + ((lg*16)      ^ rswz_r));
      bf16x8 k1 = *(const bf16x8*)((const char*)Ks + row*128 + ((64 + lg*16) ^ rswz_r));
      sc[t] = __builtin_amdgcn_mfma_f32_16x16x32_bf16(qf[0], k0, sc[t], 0,0,0);
      sc[t] = __builtin_amdgcn_mfma_f32_16x16x32_bf16(qf[1], k1, sc[t], 0,0,0);
    }

    const bool domask = (st == nst-1);
    float corr[4];
    #pragma unroll
    for (int r=0;r<4;++r){
      const int qrow = qw + lg*4 + r;
      float s0 = sc[0][r], s1 = sc[1][r], s2 = sc[2][r], s3 = sc[3][r];
      if (domask){
        const int kb = kv0 + l15;
        s0 = (kb      > qrow) ? -1e30f : s0;
        s1 = (kb + 16 > qrow) ? -1e30f : s1;
        s2 = (kb + 32 > qrow) ? -1e30f : s2;
        s3 = (kb + 48 > qrow) ? -1e30f : s3;
      }
      float mx = fmaxf(fmaxf(s0,s1), fmaxf(s2,s3));
      mx = fmaxf(mx, __shfl_xor(mx, 1));
      mx = fmaxf(mx, __shfl_xor(mx, 2));
      mx = fmaxf(mx, __shfl_xor(mx, 4));
      mx = fmaxf(mx, __shfl_xor(mx, 8));
      const float nm = fmaxf(mrun[r], mx);
      const float co = exp2f((mrun[r] - nm) * 1.44269504f);
      const float p0 = exp2f((s0 - nm) * 1.44269504f);
      const float p1 = exp2f((s1 - nm) * 1.44269504f);
      const float p2 = exp2f((s2 - nm) * 1.44269504f);
      const float p3 = exp2f((s3 - nm) * 1.44269504f);
      sc[0][r]=p0; sc[1][r]=p1; sc[2][r]=p2; sc[3][r]=p3;
      float rs = (p0+p1)+(p2+p3);
      rs += __shfl_xor(rs, 1);
      rs += __shfl_xor(rs, 2);
      rs += __shfl_xor(rs, 4);
      rs += __shfl_xor(rs, 8);
      lrun[r] = lrun[r]*co + rs;
      mrun[r] = nm;
      corr[r] = co;
    }
    #pragma unroll
    for (int c=0;c<4;++c)
      #pragma unroll
      for (int r=0;r<4;++r)
        oacc[c][r] *= corr[r];

    // P (bf16) -> per-wave swizzled LDS tile [16 q][64 k] (wave-local, no barrier)
    #pragma unroll
    for (int r=0;r<4;++r){
      const int prow = lg*4 + r;
      const int ps = (prow & 7) << 4;
      #pragma unroll
      for (int t=0;t<4;++t)
        *(__bf16*)(Pw + prow*128 + ((t*32 + l15*2) ^ ps)) = (__bf16)sc[t][r];
    }
    // PV : oacc[c] += P[16x64] @ V[64x64] (two K=32 chunks)
    #pragma unroll
    for (int t=0;t<2;++t){
      bf16x8 pa = *(const bf16x8*)(Pw + l15*128 + ((t*64 + lg*16) ^ rswz_r));
      #pragma unroll
      for (int c=0;c<4;++c){
        const int vrow = c*16 + l15;
        bf16x8 vf = *(const bf16x8*)((const char*)Vs + vrow*128 + ((t*64 + lg*16) ^ rswz_r));
        oacc[c] = __builtin_amdgcn_mfma_f32_16x16x32_bf16(pa, vf, oacc[c], 0,0,0);
      }
    }
  }

  const int b_ = bh >> 4, h_ = bh & 15;
  #pragma unroll
  for (int c=0;c<4;++c)
    #pragma unroll
    for (int r=0;r<4;++r){
      const int row = qw + lg*4 + r;
      out[((size_t)(b_*2048 + row))*1024 + h_*64 + c*16 + l15] = (__bf16)(oacc[c][r] / lrun[r]);
    }
}

extern "C" void kernel_launch(void* const* d_in, const int* in_sizes, int n_in,
                              void* d_out, int out_size, void* d_ws, size_t ws_size,
                              hipStream_t stream) {
  const float* x      = (const float*)d_in[0];
  const float* ln1_g  = (const float*)d_in[1];
  const float* ln1_b  = (const float*)d_in[2];
  const float* w_qkv  = (const float*)d_in[3];
  const float* b_qkv  = (const float*)d_in[4];
  const float* w_dense= (const float*)d_in[5];
  const float* b_dense= (const float*)d_in[6];
  const float* ln2_g  = (const float*)d_in[7];
  const float* ln2_b  = (const float*)d_in[8];
  const float* w_fc1  = (const float*)d_in[9];
  const float* w_fc2  = (const float*)d_in[10];
  const float* b_fc2  = (const float*)d_in[11];

  char* ws = (char*)d_ws;
  __bf16* wqkvT  = (__bf16*)(ws + 0);          // [3072][1024]  6 MB
  __bf16* wdenT  = (__bf16*)(ws + 6291456);    // [1024][1024]  2 MB
  __bf16* wfc1T  = (__bf16*)(ws + 8388608);    // [2048][1024]  4 MB
  __bf16* wfc2T  = (__bf16*)(ws + 12582912);   // [1024][2048]  4 MB
  __bf16* xn     = (__bf16*)(ws + 16777216);   // [4096][1024]  8 MB
  __bf16* Qb     = (__bf16*)(ws + 25165824);   // [32][2048][64] 8 MB
  __bf16* Kb     = (__bf16*)(ws + 33554432);   // [32][2048][64] 8 MB
  __bf16* Vtb    = (__bf16*)(ws + 41943040);   // [32][64][2048] 8 MB
  __bf16* attnb  = (__bf16*)(ws + 50331648);   // [4096][1024]  8 MB
  float*  outf   = (float*) (ws + 58720256);   // [4096][1024] 16 MB
  __bf16* mb     = (__bf16*)(ws + 75497472);   // [4096][1024]  8 MB
  __bf16* h1b    = (__bf16*)(ws + 83886080);   // [4096][2048] 16 MB

  dim3 blkT(32,8);
  transpose_cvt<<<dim3(3072/32, 1024/32), blkT, 0, stream>>>(w_qkv,   wqkvT, 1024, 3072);
  transpose_cvt<<<dim3(1024/32, 1024/32), blkT, 0, stream>>>(w_dense, wdenT, 1024, 1024);
  transpose_cvt<<<dim3(2048/32, 1024/32), blkT, 0, stream>>>(w_fc1,   wfc1T, 1024, 2048);
  transpose_cvt<<<dim3(1024/32, 2048/32), blkT, 0, stream>>>(w_fc2,   wfc2T, 2048, 1024);
  ln_kernel<<<4096, 256, 0, stream>>>(x, ln1_g, ln1_b, xn);
  gemm_bt<0><<<dim3(32,24), 256, 0, stream>>>(xn, wqkvT, b_qkv, nullptr,
                                              nullptr, nullptr, Qb, Kb, Vtb, 4096, 3072, 1024);
  attn_kernel<<<dim3(32,32), 256, 0, stream>>>(Qb, Kb, Vtb, attnb);
  gemm_bt<1><<<dim3(32,8), 256, 0, stream>>>(attnb, wdenT, b_dense, x,
                                             outf, nullptr, nullptr, nullptr, nullptr, 4096, 1024, 1024);
  ln_kernel<<<4096, 256, 0, stream>>>(outf, ln2_g, ln2_b, mb);
  gemm_bt<2><<<dim3(32,16), 256, 0, stream>>>(mb, wfc1T, nullptr, nullptr,
                                              nullptr, h1b, nullptr, nullptr, nullptr, 4096, 2048, 1024);
  gemm_bt<1><<<dim3(32,8), 256, 0, stream>>>(h1b, wfc2T, b_fc2, outf,
                                             (float*)d_out, nullptr, nullptr, nullptr, nullptr, 4096, 1024, 2048);
}

// Round 3
// 259.570 us; speedup vs baseline: 1.5140x; 1.2409x over previous
//
#include <hip/hip_runtime.h>
#include <hip/hip_bf16.h>

typedef __bf16 bf16x8 __attribute__((ext_vector_type(8)));
typedef float  f32x4  __attribute__((ext_vector_type(4)));

typedef __attribute__((address_space(3))) unsigned int as3_u32;
typedef __attribute__((address_space(1))) unsigned int as1_u32;

__device__ __forceinline__ void gld_lds16(const void* gptr, void* lptr){
  __builtin_amdgcn_global_load_lds((const as1_u32*)gptr, (as3_u32*)lptr, 16, 0, 0);
}

// ---------------- weight convert + transpose: in[R][C] f32 -> out[C][R] bf16
__global__ __launch_bounds__(256) void transpose_cvt(const float* __restrict__ in,
                                                     __bf16* __restrict__ out, int R, int C){
  __shared__ float tile[32][33];
  const int c0 = blockIdx.x*32, r0 = blockIdx.y*32;
  const int tx = threadIdx.x, ty = threadIdx.y;
  #pragma unroll
  for (int i=0;i<32;i+=8)
    tile[ty+i][tx] = in[(size_t)(r0+ty+i)*C + c0+tx];
  __syncthreads();
  #pragma unroll
  for (int i=0;i<32;i+=8)
    out[(size_t)(c0+ty+i)*R + r0+tx] = (__bf16)tile[tx][ty+i];
}

// ---------------- layernorm: rows of 1024 f32 -> bf16
__global__ __launch_bounds__(256) void ln_kernel(const float* __restrict__ x, const float* __restrict__ g,
                                                 const float* __restrict__ b, __bf16* __restrict__ out){
  const int row = blockIdx.x, t = threadIdx.x;
  const float4 v = ((const float4*)(x + (size_t)row*1024))[t];
  float s = v.x+v.y+v.z+v.w;
  #pragma unroll
  for (int m=1;m<64;m<<=1) s += __shfl_xor(s, m);
  __shared__ float red[8];
  if ((t&63)==0) red[t>>6] = s;
  __syncthreads();
  const float mu = (red[0]+red[1]+red[2]+red[3]) * (1.f/1024.f);
  const float d0=v.x-mu, d1=v.y-mu, d2=v.z-mu, d3=v.w-mu;
  float sq = d0*d0+d1*d1+d2*d2+d3*d3;
  #pragma unroll
  for (int m=1;m<64;m<<=1) sq += __shfl_xor(sq, m);
  if ((t&63)==0) red[4+(t>>6)] = sq;
  __syncthreads();
  const float var = (red[4]+red[5]+red[6]+red[7]) * (1.f/1024.f);
  const float inv = rsqrtf(var + 1e-12f);
  const float4 gv = ((const float4*)g)[t];
  const float4 bv = ((const float4*)b)[t];
  union { __bf16 h[4]; uint2 u; } pk;
  pk.h[0]=(__bf16)(d0*inv*gv.x+bv.x); pk.h[1]=(__bf16)(d1*inv*gv.y+bv.y);
  pk.h[2]=(__bf16)(d2*inv*gv.z+bv.z); pk.h[3]=(__bf16)(d3*inv*gv.w+bv.w);
  *(uint2*)(out + (size_t)row*1024 + t*4) = pk.u;
}

// ---------------- GEMM: C[M,N] = A[M,K](bf16,row) @ Bt[N,K](bf16,row)^T + bias, fused epilogues
template<int MODE>
__global__ __launch_bounds__(256) void gemm_bt(
    const __bf16* __restrict__ A, const __bf16* __restrict__ Bt,
    const float* __restrict__ bias, const float* __restrict__ resid,
    float* __restrict__ outF, __bf16* __restrict__ outB,
    __bf16* __restrict__ qO, __bf16* __restrict__ kO, __bf16* __restrict__ vtO,
    int M, int N, int K)
{
  __shared__ __align__(16) __bf16 As[128*32];
  __shared__ __align__(16) __bf16 Bs[128*32];
  const int tid = threadIdx.x;
  const int lane = tid & 63, wave = tid >> 6;
  const int wr = wave >> 1, wc = wave & 1;
  const int l15 = lane & 15, lg = lane >> 4;
  const int bm = blockIdx.x, bn = blockIdx.y;
  const __bf16* Ab = A  + (size_t)bm*128*K;
  const __bf16* Bb = Bt + (size_t)bn*128*K;
  f32x4 acc[4][4] = {};
  const int r0 = tid >> 2;
  const int c0 = (tid & 3) * 8;
  char* lA0 = (char*)As + wave*1024;
  char* lA1 = (char*)As + 4096 + wave*1024;
  char* lB0 = (char*)Bs + wave*1024;
  char* lB1 = (char*)Bs + 4096 + wave*1024;
  const int nk = K >> 5;
  for (int kt = 0; kt < nk; ++kt){
    __syncthreads();
    const int k0 = kt*32;
    gld_lds16(Ab + (size_t)r0*K      + k0 + c0, lA0);
    gld_lds16(Ab + (size_t)(r0+64)*K + k0 + c0, lA1);
    gld_lds16(Bb + (size_t)r0*K      + k0 + c0, lB0);
    gld_lds16(Bb + (size_t)(r0+64)*K + k0 + c0, lB1);
    __syncthreads();
    bf16x8 af[4], bfv[4];
    #pragma unroll
    for (int i=0;i<4;++i){
      af[i]  = *(const bf16x8*)&As[(wr*64 + i*16 + l15)*32 + lg*8];
      bfv[i] = *(const bf16x8*)&Bs[(wc*64 + i*16 + l15)*32 + lg*8];
    }
    #pragma unroll
    for (int i=0;i<4;++i)
      #pragma unroll
      for (int j=0;j<4;++j)
        acc[i][j] = __builtin_amdgcn_mfma_f32_16x16x32_bf16(af[i], bfv[j], acc[i][j], 0,0,0);
  }
  #pragma unroll
  for (int i=0;i<4;++i){
    #pragma unroll
    for (int j=0;j<4;++j){
      const int col = bn*128 + wc*64 + j*16 + l15;
      float bv;
      if constexpr (MODE==2) bv = 0.f; else bv = bias[col];
      #pragma unroll
      for (int r=0;r<4;++r){
        const int row = bm*128 + wr*64 + i*16 + lg*4 + r;
        float v = acc[i][j][r] + bv;
        if constexpr (MODE==0){
          const int b_ = row >> 11, s_ = row & 2047;
          if (col < 1024){
            const int h = col>>6, d = col&63;
            qO[((size_t)(b_*16+h)*2048 + s_)*64 + d] = (__bf16)v;
          } else if (col < 2048){
            const int h = (col-1024)>>6, d = (col-1024)&63;
            kO[((size_t)(b_*16+h)*2048 + s_)*64 + d] = (__bf16)v;
          } else {
            const int h = (col-2048)>>6, d = (col-2048)&63;
            vtO[((size_t)(b_*16+h)*64 + d)*2048 + s_] = (__bf16)v;
          }
        } else if constexpr (MODE==1){
          outF[(size_t)row*N + col] = v + resid[(size_t)row*N + col];
        } else {
          const float gl = 0.5f*v*(1.f + erff(v*0.70710678118f));
          outB[(size_t)row*N + col] = (__bf16)gl;
        }
      }
    }
  }
}

// ---------------- flash attention v3, causal.
// Block: 512 threads / 8 waves, 128 q-rows (16/wave). KVBLK=64, double-buffered LDS,
// stage-before-compute pipeline, swapped QK^T (lane owns one q-row -> in-lane softmax).
// Q,K: [bh][s][64] bf16 ; Vt: [bh][64][s] bf16 ; out: [b*2048+s][h*64+d] bf16
__global__ __launch_bounds__(512, 4) void attn_kernel(
    const __bf16* __restrict__ Q, const __bf16* __restrict__ K,
    const __bf16* __restrict__ Vt, __bf16* __restrict__ out)
{
  __shared__ __align__(16) __bf16 Ks[2][64*64];
  __shared__ __align__(16) __bf16 Vs[2][64*64];
  __shared__ __align__(16) __bf16 Pl[8][16*64];
  const int tid = threadIdx.x;
  const int lane = tid & 63, wave = tid >> 6;
  const int l15 = lane & 15, lg = lane >> 4;
  const int bh = blockIdx.y;
  const int qblk = (int)(gridDim.x - 1) - blockIdx.x;   // longest blocks first
  const int qb = qblk * 128;
  const int qw = qb + wave*16;                          // wave's first q-row
  const __bf16* Qh = Q + (size_t)bh*2048*64;
  const char*  Khc = (const char*)(K  + (size_t)bh*2048*64);
  const char*  Vhc = (const char*)(Vt + (size_t)bh*64*2048);

  // Q fragments (B-operand), pre-scaled by 1/sqrt(64)=0.125 (exact in bf16)
  bf16x8 qf[2];
  #pragma unroll
  for (int f=0;f<2;++f){
    bf16x8 t8 = *(const bf16x8*)&Qh[(size_t)(qw + l15)*64 + f*32 + lg*8];
    #pragma unroll
    for (int j=0;j<8;++j) t8[j] = (__bf16)((float)t8[j] * 0.125f);
    qf[f] = t8;
  }

  f32x4 oacc[4] = {};
  float mrun = -1e30f, lrun = 0.f;

  // staging source swizzle (involution): LDS linear dest, source col16 ^= row&7
  const int swz_st = (((lane&7) ^ (lane>>3)) << 4);
  const int rswz = ((l15 & 7) << 4);                    // read-side swizzle (row%8 == l15%8)
  const int srow = wave*8 + (lane>>3);                  // staging row 0..63
  char* Pw = (char*)&Pl[wave][0];
  char* ldsK[2] = { (char*)&Ks[0][0] + wave*1024, (char*)&Ks[1][0] + wave*1024 };
  char* ldsV[2] = { (char*)&Vs[0][0] + wave*1024, (char*)&Vs[1][0] + wave*1024 };

  const int nst = qblk*2 + 2;

  // prologue: stage tile 0 into buffer 0
  gld_lds16(Khc + (size_t)srow*128 + swz_st, ldsK[0]);
  gld_lds16(Vhc + (size_t)srow*4096 + swz_st, ldsV[0]);
  __syncthreads();

  for (int st = 0; st < nst; ++st){
    const int cur = st & 1;
    const int kv0 = st*64;
    // issue next tile's loads first (latency hides under compute)
    if (st+1 < nst){
      const size_t nkv0 = (size_t)(kv0 + 64);
      gld_lds16(Khc + (nkv0 + srow)*128 + swz_st, ldsK[cur^1]);
      gld_lds16(Vhc + (size_t)srow*4096 + nkv0*2 + swz_st, ldsV[cur^1]);
    }
    if (kv0 <= qw + 15){                                // wave-uniform; else fully masked
      const char* Kb = (const char*)&Ks[cur][0];
      const char* Vb = (const char*)&Vs[cur][0];
      // QK^T swapped: sc[t][r] = score(k = kv0+t*16+lg*4+r, q = qw+l15), pre-scaled
      f32x4 sc[4] = {};
      #pragma unroll
      for (int t=0;t<4;++t){
        const int row = t*16 + l15;
        bf16x8 k0 = *(const bf16x8*)(Kb + row*128 + ((lg*16)      ^ rswz));
        bf16x8 k1 = *(const bf16x8*)(Kb + row*128 + ((64 + lg*16) ^ rswz));
        sc[t] = __builtin_amdgcn_mfma_f32_16x16x32_bf16(k0, qf[0], sc[t], 0,0,0);
        sc[t] = __builtin_amdgcn_mfma_f32_16x16x32_bf16(k1, qf[1], sc[t], 0,0,0);
      }
      // causal mask (only near diagonal)
      if (kv0 + 63 > qw){
        const int q = qw + l15;
        #pragma unroll
        for (int t=0;t<4;++t)
          #pragma unroll
          for (int r=0;r<4;++r)
            if (kv0 + t*16 + lg*4 + r > q) sc[t][r] = -1e30f;
      }
      // in-lane softmax over 16 regs + 2 shuffles across lg groups
      f32x4 m01, m23;
      #pragma unroll
      for (int r=0;r<4;++r){ m01[r] = fmaxf(sc[0][r], sc[1][r]); m23[r] = fmaxf(sc[2][r], sc[3][r]); }
      float mx = fmaxf(fmaxf(fmaxf(m01[0],m23[0]), fmaxf(m01[1],m23[1])),
                       fmaxf(fmaxf(m01[2],m23[2]), fmaxf(m01[3],m23[3])));
      mx = fmaxf(mx, __shfl_xor(mx, 16));
      mx = fmaxf(mx, __shfl_xor(mx, 32));
      const float nm = fmaxf(mrun, mx);
      const float co = exp2f((mrun - nm) * 1.44269504f);
      #pragma unroll
      for (int t=0;t<4;++t)
        #pragma unroll
        for (int r=0;r<4;++r)
          sc[t][r] = exp2f((sc[t][r] - nm) * 1.44269504f);
      f32x4 s01, s23;
      #pragma unroll
      for (int r=0;r<4;++r){ s01[r] = sc[0][r]+sc[1][r]; s23[r] = sc[2][r]+sc[3][r]; }
      float rs = ((s01[0]+s23[0])+(s01[1]+s23[1])) + ((s01[2]+s23[2])+(s01[3]+s23[3]));
      rs += __shfl_xor(rs, 16);
      rs += __shfl_xor(rs, 32);
      lrun = lrun*co + rs;
      mrun = nm;
      // rescale O accumulators (corr for q-row lg*4+r lives in lane l15 = lg*4+r)
      float cor[4];
      #pragma unroll
      for (int r=0;r<4;++r) cor[r] = __shfl(co, lg*4+r);
      #pragma unroll
      for (int c=0;c<4;++c)
        #pragma unroll
        for (int r=0;r<4;++r)
          oacc[c][r] *= cor[r];
      // P -> per-wave swizzled LDS tile [16 q][64 k], packed b32 writes
      #pragma unroll
      for (int t=0;t<4;++t)
        #pragma unroll
        for (int r=0;r<4;r+=2){
          union { __bf16 h[2]; unsigned u; } pk2;
          pk2.h[0] = (__bf16)sc[t][r];
          pk2.h[1] = (__bf16)sc[t][r+1];
          *(unsigned*)(Pw + l15*128 + ((t*32 + lg*8 + r*2) ^ rswz)) = pk2.u;
        }
      // PV: oacc[c] += P[16x64] @ V^T[64 d][64 k]^T  (two K=32 chunks)
      #pragma unroll
      for (int f=0;f<2;++f){
        bf16x8 pa = *(const bf16x8*)(Pw + l15*128 + ((f*64 + lg*16) ^ rswz));
        #pragma unroll
        for (int c=0;c<4;++c){
          bf16x8 vf = *(const bf16x8*)(Vb + (c*16+l15)*128 + ((f*64 + lg*16) ^ rswz));
          oacc[c] = __builtin_amdgcn_mfma_f32_16x16x32_bf16(pa, vf, oacc[c], 0,0,0);
        }
      }
    }
    __syncthreads();   // drains vmcnt(0): next tile ready; all waves done reading cur
  }

  const int b_ = bh >> 4, h_ = bh & 15;
  float lr[4];
  #pragma unroll
  for (int r=0;r<4;++r) lr[r] = __shfl(lrun, lg*4+r);
  #pragma unroll
  for (int c=0;c<4;++c)
    #pragma unroll
    for (int r=0;r<4;++r){
      const int row = qw + lg*4 + r;
      out[((size_t)(b_*2048 + row))*1024 + h_*64 + c*16 + l15] = (__bf16)(oacc[c][r] / lr[r]);
    }
}

extern "C" void kernel_launch(void* const* d_in, const int* in_sizes, int n_in,
                              void* d_out, int out_size, void* d_ws, size_t ws_size,
                              hipStream_t stream) {
  const float* x      = (const float*)d_in[0];
  const float* ln1_g  = (const float*)d_in[1];
  const float* ln1_b  = (const float*)d_in[2];
  const float* w_qkv  = (const float*)d_in[3];
  const float* b_qkv  = (const float*)d_in[4];
  const float* w_dense= (const float*)d_in[5];
  const float* b_dense= (const float*)d_in[6];
  const float* ln2_g  = (const float*)d_in[7];
  const float* ln2_b  = (const float*)d_in[8];
  const float* w_fc1  = (const float*)d_in[9];
  const float* w_fc2  = (const float*)d_in[10];
  const float* b_fc2  = (const float*)d_in[11];

  char* ws = (char*)d_ws;
  __bf16* wqkvT  = (__bf16*)(ws + 0);          // [3072][1024]  6 MB
  __bf16* wdenT  = (__bf16*)(ws + 6291456);    // [1024][1024]  2 MB
  __bf16* wfc1T  = (__bf16*)(ws + 8388608);    // [2048][1024]  4 MB
  __bf16* wfc2T  = (__bf16*)(ws + 12582912);   // [1024][2048]  4 MB
  __bf16* xn     = (__bf16*)(ws + 16777216);   // [4096][1024]  8 MB
  __bf16* Qb     = (__bf16*)(ws + 25165824);   // [32][2048][64] 8 MB
  __bf16* Kb     = (__bf16*)(ws + 33554432);   // [32][2048][64] 8 MB
  __bf16* Vtb    = (__bf16*)(ws + 41943040);   // [32][64][2048] 8 MB
  __bf16* attnb  = (__bf16*)(ws + 50331648);   // [4096][1024]  8 MB
  float*  outf   = (float*) (ws + 58720256);   // [4096][1024] 16 MB
  __bf16* mb     = (__bf16*)(ws + 75497472);   // [4096][1024]  8 MB
  __bf16* h1b    = (__bf16*)(ws + 83886080);   // [4096][2048] 16 MB

  dim3 blkT(32,8);
  transpose_cvt<<<dim3(3072/32, 1024/32), blkT, 0, stream>>>(w_qkv,   wqkvT, 1024, 3072);
  transpose_cvt<<<dim3(1024/32, 1024/32), blkT, 0, stream>>>(w_dense, wdenT, 1024, 1024);
  transpose_cvt<<<dim3(2048/32, 1024/32), blkT, 0, stream>>>(w_fc1,   wfc1T, 1024, 2048);
  transpose_cvt<<<dim3(1024/32, 2048/32), blkT, 0, stream>>>(w_fc2,   wfc2T, 2048, 1024);
  ln_kernel<<<4096, 256, 0, stream>>>(x, ln1_g, ln1_b, xn);
  gemm_bt<0><<<dim3(32,24), 256, 0, stream>>>(xn, wqkvT, b_qkv, nullptr,
                                              nullptr, nullptr, Qb, Kb, Vtb, 4096, 3072, 1024);
  attn_kernel<<<dim3(16,32), 512, 0, stream>>>(Qb, Kb, Vtb, attnb);
  gemm_bt<1><<<dim3(32,8), 256, 0, stream>>>(attnb, wdenT, b_dense, x,
                                             outf, nullptr, nullptr, nullptr, nullptr, 4096, 1024, 1024);
  ln_kernel<<<4096, 256, 0, stream>>>(outf, ln2_g, ln2_b, mb);
  gemm_bt<2><<<dim3(32,16), 256, 0, stream>>>(mb, wfc1T, nullptr, nullptr,
                                              nullptr, h1b, nullptr, nullptr, nullptr, 4096, 2048, 1024);
  gemm_bt<1><<<dim3(32,8), 256, 0, stream>>>(h1b, wfc2T, b_fc2, outf,
                                             (float*)d_out, nullptr, nullptr, nullptr, nullptr, 4096, 1024, 2048);
}